// Round 11
// baseline (439.287 us; speedup 1.0000x reference)
//
#include <hip/hip_runtime.h>
#include <hip/hip_bf16.h>
#include <hip/hip_cooperative_groups.h>

namespace cg = cooperative_groups;

#define BLK 256
#define SCAT_NB 512        // blocks in the cooperative build kernel
#define BIN_SHIFT 8        // 256 nodes per bin

typedef unsigned short ushort_t;
typedef unsigned int uint_t;
typedef unsigned long long ull_t;
typedef __attribute__((ext_vector_type(8))) short bf16x8;
typedef __attribute__((ext_vector_type(4))) float f32x4;

static __device__ __forceinline__ float bf2f(ushort_t u) {
    return __uint_as_float((uint_t)u << 16);
}
static __device__ __forceinline__ ushort_t f2bf(float f) {
    __hip_bfloat16 h = __float2bfloat16(f);   // RNE
    return *reinterpret_cast<ushort_t*>(&h);
}

// ---------------- cooperative preprocessing: everything in ONE dispatch ----------------
// R10 post-mortem: pipeline launch-overhead bound (12 dispatches). The 6-dispatch
// CSR-build chain becomes one cooperative kernel with grid.sync() phase barriers:
// P1 bin_count + x->bf16 + W->Wt(bf16)   (512 blocks + grid-stride conversions)
// P2 scan bin-offset table (chunk scans, then block-0 carry scan)
// P3 scatter edges into bin-major buffers (LDS ranks, no global atomics)
// P4 per-bin histogram -> dinv/selfn/rowptr (LDS u64 packed cnt|fixpoint-deg + LDS scan)
// P5 per-bin emit into contiguous CSR regions

__global__ __launch_bounds__(256) void k_build(
    const int* __restrict__ eidx, const float* __restrict__ ea,
    int nbins, int epb, int E, int N,
    const float* __restrict__ x, ushort_t* __restrict__ xb, int n4,
    const float* __restrict__ W1, ushort_t* __restrict__ Wt1,
    const float* __restrict__ W2, ushort_t* __restrict__ Wt2,
    const float* __restrict__ W3, ushort_t* __restrict__ Wt3,
    int* __restrict__ bcnt, int* __restrict__ ebofs, int* __restrict__ bsumB,
    int2* __restrict__ binned_sd, float* __restrict__ binned_ea,
    float* __restrict__ dinv, float* __restrict__ selfn, int* __restrict__ rowptr,
    int* __restrict__ csr_src, float* __restrict__ csr_val)
{
    cg::grid_group grid = cg::this_grid();
    __shared__ ull_t smem64[256];     // 2 KB (P4 hist; P3 lofs)
    __shared__ int   smemi[256];      // 1 KB (histograms / scan tiles)
    const int b = blockIdx.x;
    const int t = threadIdx.x;
    const int nb = gridDim.x;         // SCAT_NB

    // ---- P1: per-(block,bin) edge counts + dtype conversions ----
    {
        int* h = smemi;
        h[t] = 0;
        __syncthreads();
        const int base = b * epb;
        const int lim  = min(base + epb, E);
        for (int e = base + t; e < lim; e += 256)
            atomicAdd(&h[eidx[E + e] >> BIN_SHIFT], 1);
        __syncthreads();
        if (t < nbins) bcnt[(size_t)t * SCAT_NB + b] = h[t];
        const int wtot = 128 * 128 + 128 * 64 + 64 * 32;
        for (int i = b * 256 + t; i < n4 + wtot; i += nb * 256) {
            if (i < n4) {
                float4 v = ((const float4*)x)[i];
                ((ushort4*)xb)[i] = make_ushort4(f2bf(v.x), f2bf(v.y), f2bf(v.z), f2bf(v.w));
            } else {
                int j = i - n4;
                if (j < 128 * 128) { int r = j / 128, c = j % 128; Wt1[(size_t)c * 128 + r] = f2bf(W1[j]); }
                else if (j < 128 * 128 + 128 * 64) { j -= 128 * 128; int r = j / 64, c = j % 64; Wt2[(size_t)c * 128 + r] = f2bf(W2[j]); }
                else { j -= 128 * 128 + 128 * 64; int r = j / 32, c = j % 32; Wt3[(size_t)c * 64 + r] = f2bf(W3[j]); }
            }
        }
    }
    grid.sync();

    // ---- P2a: per-256-chunk local scans of bcnt -> ebofs, chunk totals -> bsumB ----
    const int nbc = nbins * SCAT_NB;
    const int nchunk = (nbc + 255) / 256;
    {
        int* tile = smemi;
        for (int c = b; c < nchunk; c += nb) {
            int i = c * 256 + t;
            int v = (i < nbc) ? bcnt[i] : 0;
            tile[t] = v;
            __syncthreads();
            for (int off = 1; off < 256; off <<= 1) {
                int xx = (t >= off) ? tile[t - off] : 0;
                __syncthreads();
                tile[t] += xx;
                __syncthreads();
            }
            if (i < nbc) ebofs[i] = tile[t] - v;
            if (t == 255) bsumB[c] = tile[255];
            __syncthreads();
        }
    }
    grid.sync();

    // ---- P2b: block 0 serial-tile carry scan of bsumB ----
    if (b == 0) {
        int* tile = smemi;
        __shared__ int carry_s;
        if (t == 0) carry_s = 0;
        __syncthreads();
        for (int base2 = 0; base2 < nchunk; base2 += 256) {
            int i = base2 + t;
            int v = (i < nchunk) ? bsumB[i] : 0;
            tile[t] = v;
            __syncthreads();
            for (int off = 1; off < 256; off <<= 1) {
                int xx = (t >= off) ? tile[t - off] : 0;
                __syncthreads();
                tile[t] += xx;
                __syncthreads();
            }
            int carry = carry_s;
            if (i < nchunk) bsumB[i] = carry + tile[t] - v;
            __syncthreads();
            if (t == 255) carry_s = carry + tile[255];
            __syncthreads();
        }
    }
    grid.sync();

    // ---- P3: scatter edges into bin-major buffers ----
    {
        int* h = smemi;
        int* lofs = (int*)smem64;
        h[t] = 0;
        if (t < nbins) {
            int idx = t * SCAT_NB + b;
            lofs[t] = ebofs[idx] + bsumB[idx >> 8];
        }
        __syncthreads();
        const int base = b * epb;
        const int lim  = min(base + epb, E);
        for (int e = base + t; e < lim; e += 256) {
            int s = eidx[e];
            int d = eidx[E + e];
            float w = ea[e];
            int bin = d >> BIN_SHIFT;
            int r = atomicAdd(&h[bin], 1);
            int pos = lofs[bin] + r;
            binned_sd[pos] = make_int2(s, d);
            binned_ea[pos] = w;
        }
    }
    grid.sync();

    // ---- P4: per-bin hist -> dinv/selfn + rowptr via LDS scan ----
    if (b < nbins) {
        ull_t* hs = smem64;
        int* sc = smemi;
        hs[t] = 0ull;
        __syncthreads();
        const int i0 = b * SCAT_NB;
        const int start = ebofs[i0] + bsumB[i0 >> 8];
        int end = E;
        if (b + 1 < nbins) { int i1 = (b + 1) * SCAT_NB; end = ebofs[i1] + bsumB[i1 >> 8]; }
        for (int i = start + t; i < end; i += 256) {
            int d = binned_sd[i].y;
            atomicAdd(&hs[d & 255], (1ull << 40) | (ull_t)(binned_ea[i] * 4294967296.0f));
        }
        __syncthreads();
        int v = (int)(hs[t] >> 40);
        sc[t] = v;
        __syncthreads();
        for (int off = 1; off < 256; off <<= 1) {
            int xx = (t >= off) ? sc[t - off] : 0;
            __syncthreads();
            sc[t] += xx;
            __syncthreads();
        }
        const int node = (b << BIN_SHIFT) + t;
        if (node < N) {
            ull_t s = hs[t];
            float dg = 1.0f + (float)(s & ((1ull << 40) - 1)) * (1.0f / 4294967296.0f);
            dinv[node]  = rsqrtf(dg);
            selfn[node] = 1.0f / dg;
            rowptr[node] = start + sc[t] - v;
        }
        if (b == 0 && t == 0) rowptr[N] = E;
    }
    grid.sync();

    // ---- P5: per-bin emit into contiguous CSR region ----
    if (b < nbins) {
        int* c2 = smemi;
        c2[t] = 0;
        __syncthreads();
        const int i0 = b * SCAT_NB;
        const int start = ebofs[i0] + bsumB[i0 >> 8];
        int end = E;
        if (b + 1 < nbins) { int i1 = (b + 1) * SCAT_NB; end = ebofs[i1] + bsumB[i1 >> 8]; }
        for (int i = start + t; i < end; i += 256) {
            int2 sd = binned_sd[i];
            float w = binned_ea[i];
            int r = atomicAdd(&c2[sd.y & 255], 1);
            int pos = rowptr[sd.y] + r;
            csr_src[pos] = sd.x;
            csr_val[pos] = dinv[sd.x] * w * dinv[sd.y];
        }
    }
}

// ---------------- MFMA GEMM: C[n,FOUT](bf16) = A[n,FIN](bf16) @ Wt[FOUT,FIN]^T ----------------
// 32 rows/wave (2 row-groups share each B load). mfma_f32_16x16x32_bf16;
// A-frag row=lane&15 k=(lane>>4)*8+j; B-frag col=lane&15; C/D col=lane&15
// row=(lane>>4)*4+reg (m89-verified mapping).

template <int FIN, int FOUT>
__global__ __launch_bounds__(256) void k_gemm_mfma(const ushort_t* __restrict__ A,
                                                   const ushort_t* __restrict__ Wt,
                                                   ushort_t* __restrict__ C, int n) {
    constexpr int NT = FOUT / 16;      // col tiles
    constexpr int NK = FIN / 32;       // K steps
    const int wave = threadIdx.x >> 6;
    const int lane = threadIdx.x & 63;
    const int r0 = (blockIdx.x * 4 + wave) * 32;
    if (r0 >= n) return;

    const int l15 = lane & 15;
    const int kg  = lane >> 4;
    const int arow0 = min(r0 + l15, n - 1);        // tail clamp; bad rows never stored
    const int arow1 = min(r0 + 16 + l15, n - 1);

    f32x4 acc0[NT], acc1[NT];
#pragma unroll
    for (int c = 0; c < NT; ++c) { acc0[c] = (f32x4)(0.0f); acc1[c] = (f32x4)(0.0f); }

    const ushort_t* Ap0 = A + (size_t)arow0 * FIN + kg * 8;
    const ushort_t* Ap1 = A + (size_t)arow1 * FIN + kg * 8;
    const ushort_t* Bp  = Wt + (size_t)l15 * FIN + kg * 8;

#pragma unroll 1   // keep rolled: full unroll hoists all B loads -> spill (R1 lesson)
    for (int ks = 0; ks < NK; ++ks) {
        bf16x8 a0 = *(const bf16x8*)(Ap0 + ks * 32);
        bf16x8 a1 = *(const bf16x8*)(Ap1 + ks * 32);
#pragma unroll
        for (int c = 0; c < NT; ++c) {
            bf16x8 bfr = *(const bf16x8*)(Bp + (size_t)c * 16 * FIN + ks * 32);
            acc0[c] = __builtin_amdgcn_mfma_f32_16x16x32_bf16(a0, bfr, acc0[c], 0, 0, 0);
            acc1[c] = __builtin_amdgcn_mfma_f32_16x16x32_bf16(a1, bfr, acc1[c], 0, 0, 0);
        }
    }

#pragma unroll
    for (int g = 0; g < 2; ++g) {
        const int rbase = r0 + g * 16 + kg * 4;
#pragma unroll
        for (int c = 0; c < NT; ++c) {
#pragma unroll
            for (int j = 0; j < 4; ++j) {
                int row = rbase + j;
                float val = (g == 0) ? acc0[c][j] : acc1[c][j];
                if (row < n) C[(size_t)row * FOUT + c * 16 + l15] = f2bf(val);
            }
        }
    }
}

// ---------------- aggregation (bf16 H, ushort4 gathers, x8-unrolled) ----------------
// R10: 4 features/lane (was 2) -> 2/4/8 nodes per wave, half the load instructions,
// 2-8 independent edge streams per wave for more MLP. Per-edge gather stays one
// fully-coalesced 256B wave segment.

template <int FOUT, bool RELU, bool OBF16>
__global__ __launch_bounds__(256) void k_agg(const ushort_t* __restrict__ H,
                                             const float* __restrict__ selfn,
                                             const int* __restrict__ rowptr,
                                             const int* __restrict__ csr_src,
                                             const float* __restrict__ csr_val,
                                             const float* __restrict__ bias,
                                             void* __restrict__ outv, int n) {
    constexpr int LPN = FOUT / 4;          // lanes per node: 32 / 16 / 8
    constexpr int NPW = 64 / LPN;          // nodes per wave: 2 / 4 / 8
    const int wave = threadIdx.x >> 6;
    const int lane = threadIdx.x & 63;
    const int sub  = lane / LPN;
    const int f4   = lane % LPN;           // feature-quad index
    const int node = (blockIdx.x * 4 + wave) * NPW + sub;
    if (node >= n) return;

    const ushort_t* __restrict__ Hf = H + 4 * f4;   // lane-fixed column base

    const float sn = selfn[node];
    ushort4 hv = *(const ushort4*)(Hf + (size_t)node * FOUT);
    float a0 = sn * bf2f(hv.x);
    float a1 = sn * bf2f(hv.y);
    float a2 = sn * bf2f(hv.z);
    float a3 = sn * bf2f(hv.w);

    const int e0 = rowptr[node], e1 = rowptr[node + 1];
    int e = e0;
    for (; e + 8 <= e1; e += 8) {
        int   s0 = csr_src[e+0], s1 = csr_src[e+1], s2 = csr_src[e+2], s3 = csr_src[e+3];
        int   s4 = csr_src[e+4], s5 = csr_src[e+5], s6 = csr_src[e+6], s7 = csr_src[e+7];
        float v0 = csr_val[e+0], v1 = csr_val[e+1], v2 = csr_val[e+2], v3 = csr_val[e+3];
        float v4 = csr_val[e+4], v5 = csr_val[e+5], v6 = csr_val[e+6], v7 = csr_val[e+7];
        ushort4 m0 = *(const ushort4*)(Hf + (size_t)s0 * FOUT);
        ushort4 m1 = *(const ushort4*)(Hf + (size_t)s1 * FOUT);
        ushort4 m2 = *(const ushort4*)(Hf + (size_t)s2 * FOUT);
        ushort4 m3 = *(const ushort4*)(Hf + (size_t)s3 * FOUT);
        ushort4 m4 = *(const ushort4*)(Hf + (size_t)s4 * FOUT);
        ushort4 m5 = *(const ushort4*)(Hf + (size_t)s5 * FOUT);
        ushort4 m6 = *(const ushort4*)(Hf + (size_t)s6 * FOUT);
        ushort4 m7 = *(const ushort4*)(Hf + (size_t)s7 * FOUT);
        a0 += v0 * bf2f(m0.x); a1 += v0 * bf2f(m0.y); a2 += v0 * bf2f(m0.z); a3 += v0 * bf2f(m0.w);
        a0 += v1 * bf2f(m1.x); a1 += v1 * bf2f(m1.y); a2 += v1 * bf2f(m1.z); a3 += v1 * bf2f(m1.w);
        a0 += v2 * bf2f(m2.x); a1 += v2 * bf2f(m2.y); a2 += v2 * bf2f(m2.z); a3 += v2 * bf2f(m2.w);
        a0 += v3 * bf2f(m3.x); a1 += v3 * bf2f(m3.y); a2 += v3 * bf2f(m3.z); a3 += v3 * bf2f(m3.w);
        a0 += v4 * bf2f(m4.x); a1 += v4 * bf2f(m4.y); a2 += v4 * bf2f(m4.z); a3 += v4 * bf2f(m4.w);
        a0 += v5 * bf2f(m5.x); a1 += v5 * bf2f(m5.y); a2 += v5 * bf2f(m5.z); a3 += v5 * bf2f(m5.w);
        a0 += v6 * bf2f(m6.x); a1 += v6 * bf2f(m6.y); a2 += v6 * bf2f(m6.z); a3 += v6 * bf2f(m6.w);
        a0 += v7 * bf2f(m7.x); a1 += v7 * bf2f(m7.y); a2 += v7 * bf2f(m7.z); a3 += v7 * bf2f(m7.w);
    }
    for (; e + 2 <= e1; e += 2) {
        int   s0 = csr_src[e+0], s1 = csr_src[e+1];
        float v0 = csr_val[e+0], v1 = csr_val[e+1];
        ushort4 m0 = *(const ushort4*)(Hf + (size_t)s0 * FOUT);
        ushort4 m1 = *(const ushort4*)(Hf + (size_t)s1 * FOUT);
        a0 += v0 * bf2f(m0.x); a1 += v0 * bf2f(m0.y); a2 += v0 * bf2f(m0.z); a3 += v0 * bf2f(m0.w);
        a0 += v1 * bf2f(m1.x); a1 += v1 * bf2f(m1.y); a2 += v1 * bf2f(m1.z); a3 += v1 * bf2f(m1.w);
    }
    if (e < e1) {
        int   s0 = csr_src[e];
        float v0 = csr_val[e];
        ushort4 m0 = *(const ushort4*)(Hf + (size_t)s0 * FOUT);
        a0 += v0 * bf2f(m0.x); a1 += v0 * bf2f(m0.y); a2 += v0 * bf2f(m0.z); a3 += v0 * bf2f(m0.w);
    }

    float4 bv = *(const float4*)(bias + 4 * f4);
    a0 += bv.x; a1 += bv.y; a2 += bv.z; a3 += bv.w;
    if (RELU) {
        a0 = fmaxf(a0, 0.f); a1 = fmaxf(a1, 0.f);
        a2 = fmaxf(a2, 0.f); a3 = fmaxf(a3, 0.f);
    }
    if (OBF16) {
        ushort4 o = make_ushort4(f2bf(a0), f2bf(a1), f2bf(a2), f2bf(a3));
        *(ushort4*)((ushort_t*)outv + (size_t)node * FOUT + 4 * f4) = o;
    } else {
        *(float4*)((float*)outv + (size_t)node * FOUT + 4 * f4) = make_float4(a0, a1, a2, a3);
    }
}

// ---------------- launch ----------------

extern "C" void kernel_launch(void* const* d_in, const int* in_sizes, int n_in,
                              void* d_out, int out_size, void* d_ws, size_t ws_size,
                              hipStream_t stream) {
    const float* x    = (const float*)d_in[0];
    const int*   eidx = (const int*)d_in[1];
    const float* ea   = (const float*)d_in[2];
    const float* W1   = (const float*)d_in[3];
    const float* b1   = (const float*)d_in[4];
    const float* W2   = (const float*)d_in[5];
    const float* b2   = (const float*)d_in[6];
    const float* W3   = (const float*)d_in[7];
    const float* b3   = (const float*)d_in[8];

    const int N = in_sizes[0] / 128;
    const int E = in_sizes[2];

    int nbins = (N + 255) >> BIN_SHIFT;                  // 196 for N=50000 (<=256)
    int epb   = (E + SCAT_NB - 1) / SCAT_NB;             // edges per build block
    const int nbc = nbins * SCAT_NB;

    char*  base = (char*)d_ws;
    size_t off  = 0;
    auto carve = [&](size_t nbytes) -> void* {
        void* p = base + off;
        off = (off + nbytes + 255) & ~(size_t)255;
        return p;
    };
    int*   bcnt      = (int*)  carve((size_t)nbc * 4);
    int*   ebofs     = (int*)  carve((size_t)nbc * 4);
    int*   bsumB     = (int*)  carve((size_t)512 * 4);
    int2*  binned_sd = (int2*) carve((size_t)E * 8);
    float* binned_ea = (float*)carve((size_t)E * 4);
    float* dinv      = (float*)carve((size_t)N * 4);
    float* selfn     = (float*)carve((size_t)N * 4);
    int*   rowptr    = (int*)  carve((size_t)(N + 1) * 4);
    int*   csr_src   = (int*)  carve((size_t)E * 4);
    float* csr_val   = (float*)carve((size_t)E * 4);
    ushort_t* bufA   = (ushort_t*)carve((size_t)N * 128 * 2);   // bf16: gemm outputs H
    ushort_t* bufB   = (ushort_t*)carve((size_t)N * 128 * 2);   // bf16: xb / agg outputs G
    ushort_t* Wt1    = (ushort_t*)carve((size_t)128 * 128 * 2);
    ushort_t* Wt2    = (ushort_t*)carve((size_t)64 * 128 * 2);
    ushort_t* Wt3    = (ushort_t*)carve((size_t)32 * 64 * 2);
    (void)ws_size;

    int n4 = N * 128 / 4;                                // float4 count for x->bf16
    const int gR = (N + 127) / 128;                      // MFMA gemm blocks (128 rows/block)

    // one cooperative dispatch builds everything (R10: was 6 dispatches)
    {
        ushort_t* xb = bufB;
        int Nv = N, Ev = E;
        void* args[] = {
            (void*)&eidx, (void*)&ea, (void*)&nbins, (void*)&epb, (void*)&Ev, (void*)&Nv,
            (void*)&x, (void*)&xb, (void*)&n4,
            (void*)&W1, (void*)&Wt1, (void*)&W2, (void*)&Wt2, (void*)&W3, (void*)&Wt3,
            (void*)&bcnt, (void*)&ebofs, (void*)&bsumB,
            (void*)&binned_sd, (void*)&binned_ea,
            (void*)&dinv, (void*)&selfn, (void*)&rowptr,
            (void*)&csr_src, (void*)&csr_val
        };
        hipLaunchCooperativeKernel((const void*)k_build, dim3(SCAT_NB), dim3(BLK),
                                   args, 0, stream);
    }

    // layer 1: 128 -> 128, relu
    k_gemm_mfma<128, 128><<<gR, BLK, 0, stream>>>(bufB, Wt1, bufA, N);
    k_agg<128, true, true><<<(N + 7) / 8, BLK, 0, stream>>>(bufA, selfn, rowptr, csr_src, csr_val, b1, bufB, N);

    // layer 2: 128 -> 64, relu
    k_gemm_mfma<128, 64><<<gR, BLK, 0, stream>>>(bufB, Wt2, bufA, N);
    k_agg<64, true, true><<<(N + 15) / 16, BLK, 0, stream>>>(bufA, selfn, rowptr, csr_src, csr_val, b2, bufB, N);

    // layer 3: 64 -> 32, no relu
    k_gemm_mfma<64, 32><<<gR, BLK, 0, stream>>>(bufB, Wt3, bufA, N);
    k_agg<32, false, false><<<(N + 31) / 32, BLK, 0, stream>>>(bufA, selfn, rowptr, csr_src, csr_val, b3, d_out, N);
}

// Round 12
// 151.506 us; speedup vs baseline: 2.8995x; 2.8995x over previous
//
#include <hip/hip_runtime.h>
#include <hip/hip_bf16.h>

#define BLK 256
#define SCAT_NB 512        // blocks in the binning scatter pass
#define BIN_SHIFT 8        // 256 nodes per bin

typedef unsigned short ushort_t;
typedef unsigned int uint_t;
typedef unsigned long long ull_t;
typedef __attribute__((ext_vector_type(8))) short bf16x8;
typedef __attribute__((ext_vector_type(4))) float f32x4;

static __device__ __forceinline__ float bf2f(ushort_t u) {
    return __uint_as_float((uint_t)u << 16);
}
static __device__ __forceinline__ ushort_t f2bf(float f) {
    __hip_bfloat16 h = __float2bfloat16(f);   // RNE
    return *reinterpret_cast<ushort_t*>(&h);
}

// ---------------- fused prologue: bin_count + weight conv + x->bf16 ----------------
// R11 post-mortem: cooperative grid.sync() costs ~50-60us each on MI355X (8 XCDs,
// device-scope spin) -> k_build was 320us alone. REVERTED to the R10 multi-dispatch
// chain: kernel-launch boundaries ARE the cheap grid barrier (~2-3us each).

__global__ __launch_bounds__(256) void k_pre(const int* __restrict__ eidx,
                                             int* __restrict__ bcnt,
                                             int nbins, int epb, int E,
                                             const float* __restrict__ x,
                                             ushort_t* __restrict__ xb, int n4,
                                             const float* __restrict__ W1, ushort_t* __restrict__ Wt1,
                                             const float* __restrict__ W2, ushort_t* __restrict__ Wt2,
                                             const float* __restrict__ W3, ushort_t* __restrict__ Wt3) {
    const int b = blockIdx.x;
    const int t = threadIdx.x;
    if (b < SCAT_NB) {
        // per-(block,bin) edge counts
        __shared__ int h[256];
        h[t] = 0;
        __syncthreads();
        const int base = b * epb;
        const int lim  = min(base + epb, E);
        for (int e = base + t; e < lim; e += 256)
            atomicAdd(&h[eidx[E + e] >> BIN_SHIFT], 1);
        __syncthreads();
        if (t < nbins) bcnt[(size_t)t * SCAT_NB + b] = h[t];
    } else {
        int i = (b - SCAT_NB) * 256 + t;
        if (i < n4) {                       // x -> bf16, 4 elems/thread
            float4 v = ((const float4*)x)[i];
            ((ushort4*)xb)[i] = make_ushort4(f2bf(v.x), f2bf(v.y), f2bf(v.z), f2bf(v.w));
        } else {
            int j = i - n4;                 // W[fin][fout] -> Wt[fout][fin] bf16
            if (j < 128 * 128) {
                int r = j / 128, c = j % 128;
                Wt1[(size_t)c * 128 + r] = f2bf(W1[j]);
            } else if (j < 128 * 128 + 128 * 64) {
                j -= 128 * 128;
                int r = j / 64, c = j % 64;
                Wt2[(size_t)c * 128 + r] = f2bf(W2[j]);
            } else if (j < 128 * 128 + 128 * 64 + 64 * 32) {
                j -= 128 * 128 + 128 * 64;
                int r = j / 32, c = j % 32;
                Wt3[(size_t)c * 64 + r] = f2bf(W3[j]);
            }
        }
    }
}

// ---------------- scans for the bin-offset table ----------------

__global__ __launch_bounds__(256) void k_scan1(const int* __restrict__ cnt,
                                               int* rowptr, int* bsum, int n) {
    __shared__ int tile[256];
    const int t = threadIdx.x;
    const int i = blockIdx.x * 256 + t;
    int v = (i < n) ? cnt[i] : 0;
    tile[t] = v;
    __syncthreads();
    for (int off = 1; off < 256; off <<= 1) {
        int x = (t >= off) ? tile[t - off] : 0;
        __syncthreads();
        tile[t] += x;
        __syncthreads();
    }
    if (i < n) rowptr[i] = tile[t] - v;
    if (t == 255) bsum[blockIdx.x] = tile[255];
}

// single block, arbitrary n (serial tiles with carry), in-place exclusive
__global__ __launch_bounds__(256) void k_scan2x(int* a, int n) {
    __shared__ int tile[256];
    __shared__ int carry_s;
    const int t = threadIdx.x;
    if (t == 0) carry_s = 0;
    __syncthreads();
    for (int base = 0; base < n; base += 256) {
        int i = base + t;
        int v = (i < n) ? a[i] : 0;
        tile[t] = v;
        __syncthreads();
        for (int off = 1; off < 256; off <<= 1) {
            int x = (t >= off) ? tile[t - off] : 0;
            __syncthreads();
            tile[t] += x;
            __syncthreads();
        }
        int carry = carry_s;
        if (i < n) a[i] = carry + tile[t] - v;
        __syncthreads();
        if (t == 255) carry_s = carry + tile[255];
        __syncthreads();
    }
}

// consumers reconstruct global offsets as ebofs[idx] + bsumB[idx>>8] (scan3 folded in)

// ---------------- binned CSR build ----------------

__global__ __launch_bounds__(256) void k_bin_scatter(const int* __restrict__ eidx,
                                                     const float* __restrict__ ea,
                                                     const int* __restrict__ ebofs,
                                                     const int* __restrict__ bsumB,
                                                     int2* __restrict__ binned_sd,
                                                     float* __restrict__ binned_ea,
                                                     int nbins, int epb, int E) {
    __shared__ int h[256];
    __shared__ int lofs[256];
    const int t = threadIdx.x;
    h[t] = 0;
    if (t < nbins) {
        int idx = t * SCAT_NB + blockIdx.x;
        lofs[t] = ebofs[idx] + bsumB[idx >> 8];
    }
    __syncthreads();
    const int base = blockIdx.x * epb;
    const int lim  = min(base + epb, E);
    for (int e = base + t; e < lim; e += 256) {
        int s = eidx[e];
        int d = eidx[E + e];
        float w = ea[e];
        int bin = d >> BIN_SHIFT;
        int r = atomicAdd(&h[bin], 1);      // LDS-local rank
        int pos = lofs[bin] + r;
        binned_sd[pos] = make_int2(s, d);
        binned_ea[pos] = w;
    }
}

// per-bin histogram -> dinv/selfn AND rowptr (LDS scan; bins are node-aligned)
__global__ __launch_bounds__(256) void k_bin_hist(const int2* __restrict__ binned_sd,
                                                  const float* __restrict__ binned_ea,
                                                  const int* __restrict__ ebofs,
                                                  const int* __restrict__ bsumB,
                                                  float* __restrict__ dinv,
                                                  float* __restrict__ selfn,
                                                  int* __restrict__ rowptr,
                                                  int nbins, int N, int E) {
    __shared__ ull_t hs[256];
    __shared__ int sc[256];
    const int t = threadIdx.x;
    const int b = blockIdx.x;
    hs[t] = 0ull;
    __syncthreads();
    const int i0 = b * SCAT_NB;
    const int start = ebofs[i0] + bsumB[i0 >> 8];
    int end = E;
    if (b + 1 < nbins) {
        int i1 = (b + 1) * SCAT_NB;
        end = ebofs[i1] + bsumB[i1 >> 8];
    }
    for (int i = start + t; i < end; i += 256) {
        int d = binned_sd[i].y;
        float w = binned_ea[i];
        atomicAdd(&hs[d & 255], (1ull << 40) | (ull_t)(w * 4294967296.0f));
    }
    __syncthreads();
    int v = (int)(hs[t] >> 40);
    sc[t] = v;
    __syncthreads();
    for (int off = 1; off < 256; off <<= 1) {
        int x = (t >= off) ? sc[t - off] : 0;
        __syncthreads();
        sc[t] += x;
        __syncthreads();
    }
    const int node = (b << BIN_SHIFT) + t;
    if (node < N) {
        ull_t s = hs[t];
        float dg = 1.0f + (float)(s & ((1ull << 40) - 1)) * (1.0f / 4294967296.0f);
        dinv[node]  = rsqrtf(dg);
        selfn[node] = 1.0f / dg;
        rowptr[node] = start + sc[t] - v;
    }
    if (b == 0 && t == 0) rowptr[N] = E;
}

// per-bin emit into final (contiguous) CSR region
__global__ __launch_bounds__(256) void k_bin_emit(const int2* __restrict__ binned_sd,
                                                  const float* __restrict__ binned_ea,
                                                  const int* __restrict__ ebofs,
                                                  const int* __restrict__ bsumB,
                                                  const int* __restrict__ rowptr,
                                                  const float* __restrict__ dinv,
                                                  int* __restrict__ csr_src,
                                                  float* __restrict__ csr_val,
                                                  int nbins, int E) {
    __shared__ int c2[256];
    const int t = threadIdx.x;
    const int b = blockIdx.x;
    c2[t] = 0;
    __syncthreads();
    const int i0 = b * SCAT_NB;
    const int start = ebofs[i0] + bsumB[i0 >> 8];
    int end = E;
    if (b + 1 < nbins) {
        int i1 = (b + 1) * SCAT_NB;
        end = ebofs[i1] + bsumB[i1 >> 8];
    }
    for (int i = start + t; i < end; i += 256) {
        int2 sd = binned_sd[i];
        float w = binned_ea[i];
        int r = atomicAdd(&c2[sd.y & 255], 1);   // LDS-local rank within node
        int pos = rowptr[sd.y] + r;
        csr_src[pos] = sd.x;
        csr_val[pos] = dinv[sd.x] * w * dinv[sd.y];
    }
}

// ---------------- MFMA GEMM: C[n,FOUT](bf16) = A[n,FIN](bf16) @ Wt[FOUT,FIN]^T ----------------
// 32 rows/wave (2 row-groups share each B load). mfma_f32_16x16x32_bf16;
// A-frag row=lane&15 k=(lane>>4)*8+j; B-frag col=lane&15; C/D col=lane&15
// row=(lane>>4)*4+reg (m89-verified mapping).

template <int FIN, int FOUT>
__global__ __launch_bounds__(256) void k_gemm_mfma(const ushort_t* __restrict__ A,
                                                   const ushort_t* __restrict__ Wt,
                                                   ushort_t* __restrict__ C, int n) {
    constexpr int NT = FOUT / 16;      // col tiles
    constexpr int NK = FIN / 32;       // K steps
    const int wave = threadIdx.x >> 6;
    const int lane = threadIdx.x & 63;
    const int r0 = (blockIdx.x * 4 + wave) * 32;
    if (r0 >= n) return;

    const int l15 = lane & 15;
    const int kg  = lane >> 4;
    const int arow0 = min(r0 + l15, n - 1);        // tail clamp; bad rows never stored
    const int arow1 = min(r0 + 16 + l15, n - 1);

    f32x4 acc0[NT], acc1[NT];
#pragma unroll
    for (int c = 0; c < NT; ++c) { acc0[c] = (f32x4)(0.0f); acc1[c] = (f32x4)(0.0f); }

    const ushort_t* Ap0 = A + (size_t)arow0 * FIN + kg * 8;
    const ushort_t* Ap1 = A + (size_t)arow1 * FIN + kg * 8;
    const ushort_t* Bp  = Wt + (size_t)l15 * FIN + kg * 8;

#pragma unroll 1   // keep rolled: full unroll hoists all B loads -> spill (R1 lesson)
    for (int ks = 0; ks < NK; ++ks) {
        bf16x8 a0 = *(const bf16x8*)(Ap0 + ks * 32);
        bf16x8 a1 = *(const bf16x8*)(Ap1 + ks * 32);
#pragma unroll
        for (int c = 0; c < NT; ++c) {
            bf16x8 bfr = *(const bf16x8*)(Bp + (size_t)c * 16 * FIN + ks * 32);
            acc0[c] = __builtin_amdgcn_mfma_f32_16x16x32_bf16(a0, bfr, acc0[c], 0, 0, 0);
            acc1[c] = __builtin_amdgcn_mfma_f32_16x16x32_bf16(a1, bfr, acc1[c], 0, 0, 0);
        }
    }

#pragma unroll
    for (int g = 0; g < 2; ++g) {
        const int rbase = r0 + g * 16 + kg * 4;
#pragma unroll
        for (int c = 0; c < NT; ++c) {
#pragma unroll
            for (int j = 0; j < 4; ++j) {
                int row = rbase + j;
                float val = (g == 0) ? acc0[c][j] : acc1[c][j];
                if (row < n) C[(size_t)row * FOUT + c * 16 + l15] = f2bf(val);
            }
        }
    }
}

// ---------------- aggregation (bf16 H, ushort4 gathers, x8-unrolled) ----------------
// 4 features/lane -> 2/4/8 nodes per wave, half the load instructions, more
// independent edge streams per wave. Per-edge gather = one coalesced 256B segment.

template <int FOUT, bool RELU, bool OBF16>
__global__ __launch_bounds__(256) void k_agg(const ushort_t* __restrict__ H,
                                             const float* __restrict__ selfn,
                                             const int* __restrict__ rowptr,
                                             const int* __restrict__ csr_src,
                                             const float* __restrict__ csr_val,
                                             const float* __restrict__ bias,
                                             void* __restrict__ outv, int n) {
    constexpr int LPN = FOUT / 4;          // lanes per node: 32 / 16 / 8
    constexpr int NPW = 64 / LPN;          // nodes per wave: 2 / 4 / 8
    const int wave = threadIdx.x >> 6;
    const int lane = threadIdx.x & 63;
    const int sub  = lane / LPN;
    const int f4   = lane % LPN;           // feature-quad index
    const int node = (blockIdx.x * 4 + wave) * NPW + sub;
    if (node >= n) return;

    const ushort_t* __restrict__ Hf = H + 4 * f4;   // lane-fixed column base

    const float sn = selfn[node];
    ushort4 hv = *(const ushort4*)(Hf + (size_t)node * FOUT);
    float a0 = sn * bf2f(hv.x);
    float a1 = sn * bf2f(hv.y);
    float a2 = sn * bf2f(hv.z);
    float a3 = sn * bf2f(hv.w);

    const int e0 = rowptr[node], e1 = rowptr[node + 1];
    int e = e0;
    for (; e + 8 <= e1; e += 8) {
        int   s0 = csr_src[e+0], s1 = csr_src[e+1], s2 = csr_src[e+2], s3 = csr_src[e+3];
        int   s4 = csr_src[e+4], s5 = csr_src[e+5], s6 = csr_src[e+6], s7 = csr_src[e+7];
        float v0 = csr_val[e+0], v1 = csr_val[e+1], v2 = csr_val[e+2], v3 = csr_val[e+3];
        float v4 = csr_val[e+4], v5 = csr_val[e+5], v6 = csr_val[e+6], v7 = csr_val[e+7];
        ushort4 m0 = *(const ushort4*)(Hf + (size_t)s0 * FOUT);
        ushort4 m1 = *(const ushort4*)(Hf + (size_t)s1 * FOUT);
        ushort4 m2 = *(const ushort4*)(Hf + (size_t)s2 * FOUT);
        ushort4 m3 = *(const ushort4*)(Hf + (size_t)s3 * FOUT);
        ushort4 m4 = *(const ushort4*)(Hf + (size_t)s4 * FOUT);
        ushort4 m5 = *(const ushort4*)(Hf + (size_t)s5 * FOUT);
        ushort4 m6 = *(const ushort4*)(Hf + (size_t)s6 * FOUT);
        ushort4 m7 = *(const ushort4*)(Hf + (size_t)s7 * FOUT);
        a0 += v0 * bf2f(m0.x); a1 += v0 * bf2f(m0.y); a2 += v0 * bf2f(m0.z); a3 += v0 * bf2f(m0.w);
        a0 += v1 * bf2f(m1.x); a1 += v1 * bf2f(m1.y); a2 += v1 * bf2f(m1.z); a3 += v1 * bf2f(m1.w);
        a0 += v2 * bf2f(m2.x); a1 += v2 * bf2f(m2.y); a2 += v2 * bf2f(m2.z); a3 += v2 * bf2f(m2.w);
        a0 += v3 * bf2f(m3.x); a1 += v3 * bf2f(m3.y); a2 += v3 * bf2f(m3.z); a3 += v3 * bf2f(m3.w);
        a0 += v4 * bf2f(m4.x); a1 += v4 * bf2f(m4.y); a2 += v4 * bf2f(m4.z); a3 += v4 * bf2f(m4.w);
        a0 += v5 * bf2f(m5.x); a1 += v5 * bf2f(m5.y); a2 += v5 * bf2f(m5.z); a3 += v5 * bf2f(m5.w);
        a0 += v6 * bf2f(m6.x); a1 += v6 * bf2f(m6.y); a2 += v6 * bf2f(m6.z); a3 += v6 * bf2f(m6.w);
        a0 += v7 * bf2f(m7.x); a1 += v7 * bf2f(m7.y); a2 += v7 * bf2f(m7.z); a3 += v7 * bf2f(m7.w);
    }
    for (; e + 2 <= e1; e += 2) {
        int   s0 = csr_src[e+0], s1 = csr_src[e+1];
        float v0 = csr_val[e+0], v1 = csr_val[e+1];
        ushort4 m0 = *(const ushort4*)(Hf + (size_t)s0 * FOUT);
        ushort4 m1 = *(const ushort4*)(Hf + (size_t)s1 * FOUT);
        a0 += v0 * bf2f(m0.x); a1 += v0 * bf2f(m0.y); a2 += v0 * bf2f(m0.z); a3 += v0 * bf2f(m0.w);
        a0 += v1 * bf2f(m1.x); a1 += v1 * bf2f(m1.y); a2 += v1 * bf2f(m1.z); a3 += v1 * bf2f(m1.w);
    }
    if (e < e1) {
        int   s0 = csr_src[e];
        float v0 = csr_val[e];
        ushort4 m0 = *(const ushort4*)(Hf + (size_t)s0 * FOUT);
        a0 += v0 * bf2f(m0.x); a1 += v0 * bf2f(m0.y); a2 += v0 * bf2f(m0.z); a3 += v0 * bf2f(m0.w);
    }

    float4 bv = *(const float4*)(bias + 4 * f4);
    a0 += bv.x; a1 += bv.y; a2 += bv.z; a3 += bv.w;
    if (RELU) {
        a0 = fmaxf(a0, 0.f); a1 = fmaxf(a1, 0.f);
        a2 = fmaxf(a2, 0.f); a3 = fmaxf(a3, 0.f);
    }
    if (OBF16) {
        ushort4 o = make_ushort4(f2bf(a0), f2bf(a1), f2bf(a2), f2bf(a3));
        *(ushort4*)((ushort_t*)outv + (size_t)node * FOUT + 4 * f4) = o;
    } else {
        *(float4*)((float*)outv + (size_t)node * FOUT + 4 * f4) = make_float4(a0, a1, a2, a3);
    }
}

// ---------------- launch ----------------

extern "C" void kernel_launch(void* const* d_in, const int* in_sizes, int n_in,
                              void* d_out, int out_size, void* d_ws, size_t ws_size,
                              hipStream_t stream) {
    const float* x    = (const float*)d_in[0];
    const int*   eidx = (const int*)d_in[1];
    const float* ea   = (const float*)d_in[2];
    const float* W1   = (const float*)d_in[3];
    const float* b1   = (const float*)d_in[4];
    const float* W2   = (const float*)d_in[5];
    const float* b2   = (const float*)d_in[6];
    const float* W3   = (const float*)d_in[7];
    const float* b3   = (const float*)d_in[8];

    const int N = in_sizes[0] / 128;
    const int E = in_sizes[2];

    const int nbins = (N + 255) >> BIN_SHIFT;            // 196 for N=50000 (<=256)
    const int epb   = (E + SCAT_NB - 1) / SCAT_NB;       // edges per scatter block
    const int nbc   = nbins * SCAT_NB;                   // bcnt/ebofs length
    const int gBC   = (nbc + BLK - 1) / BLK;

    char*  base = (char*)d_ws;
    size_t off  = 0;
    auto carve = [&](size_t nbytes) -> void* {
        void* p = base + off;
        off = (off + nbytes + 255) & ~(size_t)255;
        return p;
    };
    int*   bcnt      = (int*)  carve((size_t)nbc * 4);
    int*   ebofs     = (int*)  carve((size_t)nbc * 4);
    int*   bsumB     = (int*)  carve((size_t)512 * 4);
    int2*  binned_sd = (int2*) carve((size_t)E * 8);
    float* binned_ea = (float*)carve((size_t)E * 4);
    float* dinv      = (float*)carve((size_t)N * 4);
    float* selfn     = (float*)carve((size_t)N * 4);
    int*   rowptr    = (int*)  carve((size_t)(N + 1) * 4);
    int*   csr_src   = (int*)  carve((size_t)E * 4);
    float* csr_val   = (float*)carve((size_t)E * 4);
    ushort_t* bufA   = (ushort_t*)carve((size_t)N * 128 * 2);   // bf16: gemm outputs H
    ushort_t* bufB   = (ushort_t*)carve((size_t)N * 128 * 2);   // bf16: xb / agg outputs G
    ushort_t* Wt1    = (ushort_t*)carve((size_t)128 * 128 * 2);
    ushort_t* Wt2    = (ushort_t*)carve((size_t)64 * 128 * 2);
    ushort_t* Wt3    = (ushort_t*)carve((size_t)32 * 64 * 2);
    (void)ws_size;

    const int n4 = N * 128 / 4;                          // float4 count for x->bf16
    const int gPre = SCAT_NB + (n4 + 128 * 128 + 128 * 64 + 64 * 32 + 255) / 256;
    const int gR = (N + 127) / 128;                      // MFMA gemm blocks (128 rows/block)

    // prologue: bin_count + weight transpose/convert + x->bf16 (one dispatch)
    k_pre<<<gPre, BLK, 0, stream>>>(eidx, bcnt, nbins, epb, E,
                                    x, bufB, n4, W1, Wt1, W2, Wt2, W3, Wt3);
    // scan bin offsets (global offsets reconstructed inline by consumers)
    k_scan1<<<gBC, BLK, 0, stream>>>(bcnt, ebofs, bsumB, nbc);
    k_scan2x<<<1, BLK, 0, stream>>>(bsumB, gBC);
    // binned CSR build (no global atomics); bin_hist also emits rowptr via LDS scan
    k_bin_scatter<<<SCAT_NB, BLK, 0, stream>>>(eidx, ea, ebofs, bsumB, binned_sd, binned_ea, nbins, epb, E);
    k_bin_hist<<<nbins, BLK, 0, stream>>>(binned_sd, binned_ea, ebofs, bsumB, dinv, selfn, rowptr, nbins, N, E);
    k_bin_emit<<<nbins, BLK, 0, stream>>>(binned_sd, binned_ea, ebofs, bsumB, rowptr, dinv,
                                          csr_src, csr_val, nbins, E);

    // layer 1: 128 -> 128, relu
    k_gemm_mfma<128, 128><<<gR, BLK, 0, stream>>>(bufB, Wt1, bufA, N);
    k_agg<128, true, true><<<(N + 7) / 8, BLK, 0, stream>>>(bufA, selfn, rowptr, csr_src, csr_val, b1, bufB, N);

    // layer 2: 128 -> 64, relu
    k_gemm_mfma<128, 64><<<gR, BLK, 0, stream>>>(bufB, Wt2, bufA, N);
    k_agg<64, true, true><<<(N + 15) / 16, BLK, 0, stream>>>(bufA, selfn, rowptr, csr_src, csr_val, b2, bufB, N);

    // layer 3: 64 -> 32, no relu
    k_gemm_mfma<64, 32><<<gR, BLK, 0, stream>>>(bufB, Wt3, bufA, N);
    k_agg<32, false, false><<<(N + 31) / 32, BLK, 0, stream>>>(bufA, selfn, rowptr, csr_src, csr_val, b3, d_out, N);
}

// Round 13
// 141.477 us; speedup vs baseline: 3.1050x; 1.0709x over previous
//
#include <hip/hip_runtime.h>
#include <hip/hip_bf16.h>

#define BLK 256
#define SCAT_NB 512        // blocks in the binning scatter pass
#define BIN_SHIFT 8        // 256 nodes per bin
#define STAGE_CAP 6144     // LDS-staged edges per bin (mean ~4080, 19-sigma headroom)

typedef unsigned short ushort_t;
typedef unsigned int uint_t;
typedef unsigned long long ull_t;
typedef __attribute__((ext_vector_type(8))) short bf16x8;
typedef __attribute__((ext_vector_type(4))) float f32x4;

static __device__ __forceinline__ float bf2f(ushort_t u) {
    return __uint_as_float((uint_t)u << 16);
}
static __device__ __forceinline__ ushort_t f2bf(float f) {
    __hip_bfloat16 h = __float2bfloat16(f);   // RNE
    return *reinterpret_cast<ushort_t*>(&h);
}

// ================= normalization factorization (R12) =================
// H' = dinv * (G @ W)  (row-scale in GEMM epilogue). Then:
//   message = (w * dinv[d]) * H'[s]      <- csr_val needs NO dinv[s]!
//   self    = dinv[node] * H'[node]
// This removes the cross-bin dinv[s] dependency from CSR emit, enabling
// the fused hist+emit kernel below.

// ---------------- fused prologue: bin_count + weight conv ----------------

__global__ __launch_bounds__(256) void k_pre(const int* __restrict__ eidx,
                                             int* __restrict__ bcnt,
                                             int nbins, int epb, int E,
                                             const float* __restrict__ W1, ushort_t* __restrict__ Wt1,
                                             const float* __restrict__ W2, ushort_t* __restrict__ Wt2,
                                             const float* __restrict__ W3, ushort_t* __restrict__ Wt3) {
    const int b = blockIdx.x;
    const int t = threadIdx.x;
    if (b < SCAT_NB) {
        __shared__ int h[256];
        h[t] = 0;
        __syncthreads();
        const int base = b * epb;
        const int lim  = min(base + epb, E);
        for (int e = base + t; e < lim; e += 256)
            atomicAdd(&h[eidx[E + e] >> BIN_SHIFT], 1);
        __syncthreads();
        if (t < nbins) bcnt[(size_t)t * SCAT_NB + b] = h[t];
    } else {
        int j = (b - SCAT_NB) * 256 + t;   // W[fin][fout] -> Wt[fout][fin] bf16
        if (j < 128 * 128) {
            int r = j / 128, c = j % 128;
            Wt1[(size_t)c * 128 + r] = f2bf(W1[j]);
        } else if (j < 128 * 128 + 128 * 64) {
            j -= 128 * 128;
            int r = j / 64, c = j % 64;
            Wt2[(size_t)c * 128 + r] = f2bf(W2[j]);
        } else if (j < 128 * 128 + 128 * 64 + 64 * 32) {
            j -= 128 * 128 + 128 * 64;
            int r = j / 32, c = j % 32;
            Wt3[(size_t)c * 64 + r] = f2bf(W3[j]);
        }
    }
}

// ---------------- scans for the bin-offset table ----------------

__global__ __launch_bounds__(256) void k_scan1(const int* __restrict__ cnt,
                                               int* rowptr, int* bsum, int n) {
    __shared__ int tile[256];
    const int t = threadIdx.x;
    const int i = blockIdx.x * 256 + t;
    int v = (i < n) ? cnt[i] : 0;
    tile[t] = v;
    __syncthreads();
    for (int off = 1; off < 256; off <<= 1) {
        int x = (t >= off) ? tile[t - off] : 0;
        __syncthreads();
        tile[t] += x;
        __syncthreads();
    }
    if (i < n) rowptr[i] = tile[t] - v;
    if (t == 255) bsum[blockIdx.x] = tile[255];
}

// single block, arbitrary n (serial tiles with carry), in-place exclusive
__global__ __launch_bounds__(256) void k_scan2x(int* a, int n) {
    __shared__ int tile[256];
    __shared__ int carry_s;
    const int t = threadIdx.x;
    if (t == 0) carry_s = 0;
    __syncthreads();
    for (int base = 0; base < n; base += 256) {
        int i = base + t;
        int v = (i < n) ? a[i] : 0;
        tile[t] = v;
        __syncthreads();
        for (int off = 1; off < 256; off <<= 1) {
            int x = (t >= off) ? tile[t - off] : 0;
            __syncthreads();
            tile[t] += x;
            __syncthreads();
        }
        int carry = carry_s;
        if (i < n) a[i] = carry + tile[t] - v;
        __syncthreads();
        if (t == 255) carry_s = carry + tile[255];
        __syncthreads();
    }
}

// consumers reconstruct global offsets as ebofs[idx] + bsumB[idx>>8]

// ---------------- binned edge scatter (8B packed: (s<<8)|(d&255), w) ----------------

__global__ __launch_bounds__(256) void k_bin_scatter(const int* __restrict__ eidx,
                                                     const float* __restrict__ ea,
                                                     const int* __restrict__ ebofs,
                                                     const int* __restrict__ bsumB,
                                                     uint2* __restrict__ binned,
                                                     int nbins, int epb, int E) {
    __shared__ int h[256];
    __shared__ int lofs[256];
    const int t = threadIdx.x;
    h[t] = 0;
    if (t < nbins) {
        int idx = t * SCAT_NB + blockIdx.x;
        lofs[t] = ebofs[idx] + bsumB[idx >> 8];
    }
    __syncthreads();
    const int base = blockIdx.x * epb;
    const int lim  = min(base + epb, E);
    for (int e = base + t; e < lim; e += 256) {
        int s = eidx[e];
        int d = eidx[E + e];
        float w = ea[e];
        int bin = d >> BIN_SHIFT;
        int r = atomicAdd(&h[bin], 1);      // LDS-local rank
        int pos = lofs[bin] + r;
        binned[pos] = make_uint2(((uint_t)s << 8) | (uint_t)(d & 255), __float_as_uint(w));
    }
}

// ---------------- fused per-bin hist + rowptr + dinv + CSR emit ----------------
// Stages the bin's packed edges in LDS (one global read), u64 packed hist
// (cnt | fixed-point weighted deg), LDS scan -> rowptr, then emits csr from LDS.
// csr_val = w * dinv[d] (dinv[s] folded into H' by the GEMM epilogue).

__global__ __launch_bounds__(256) void k_bin_finish(const uint2* __restrict__ binned,
                                                    const int* __restrict__ ebofs,
                                                    const int* __restrict__ bsumB,
                                                    float* __restrict__ dinv,
                                                    int* __restrict__ rowptr,
                                                    int* __restrict__ csr_src,
                                                    float* __restrict__ csr_val,
                                                    int nbins, int N, int E) {
    __shared__ uint2 stage[STAGE_CAP];   // 48 KB
    __shared__ ull_t hs[256];
    __shared__ int   sc[256];
    __shared__ int   rp[256];
    __shared__ float dl[256];
    __shared__ int   c2[256];
    const int t = threadIdx.x;
    const int b = blockIdx.x;
    hs[t] = 0ull;
    c2[t] = 0;
    __syncthreads();
    const int i0 = b * SCAT_NB;
    const int start = ebofs[i0] + bsumB[i0 >> 8];
    int end = E;
    if (b + 1 < nbins) {
        int i1 = (b + 1) * SCAT_NB;
        end = ebofs[i1] + bsumB[i1 >> 8];
    }
    const int cnt = end - start;
    const bool fits = (cnt <= STAGE_CAP);

    // phase 1: histogram (+ LDS staging when it fits)
    if (fits) {
        for (int i = t; i < cnt; i += 256) {
            uint2 p = binned[start + i];
            stage[i] = p;
            atomicAdd(&hs[p.x & 255],
                      (1ull << 40) | (ull_t)(__uint_as_float(p.y) * 4294967296.0f));
        }
    } else {
        for (int i = start + t; i < end; i += 256) {
            uint2 p = binned[i];
            atomicAdd(&hs[p.x & 255],
                      (1ull << 40) | (ull_t)(__uint_as_float(p.y) * 4294967296.0f));
        }
    }
    __syncthreads();

    // scan counts -> per-node exclusive offsets; compute dinv
    int v = (int)(hs[t] >> 40);
    sc[t] = v;
    __syncthreads();
    for (int off = 1; off < 256; off <<= 1) {
        int x = (t >= off) ? sc[t - off] : 0;
        __syncthreads();
        sc[t] += x;
        __syncthreads();
    }
    {
        ull_t s = hs[t];
        float dg = 1.0f + (float)(s & ((1ull << 40) - 1)) * (1.0f / 4294967296.0f);
        float di = rsqrtf(dg);
        dl[t] = di;
        rp[t] = start + sc[t] - v;
        const int node = (b << BIN_SHIFT) + t;
        if (node < N) {
            dinv[node]   = di;
            rowptr[node] = rp[t];
        }
        if (b == 0 && t == 0) rowptr[N] = E;
    }
    __syncthreads();

    // phase 2: emit
    if (fits) {
        for (int i = t; i < cnt; i += 256) {
            uint2 p = stage[i];
            int d8 = p.x & 255;
            int r = atomicAdd(&c2[d8], 1);
            int pos = rp[d8] + r;
            csr_src[pos] = (int)(p.x >> 8);
            csr_val[pos] = __uint_as_float(p.y) * dl[d8];
        }
    } else {
        for (int i = start + t; i < end; i += 256) {
            uint2 p = binned[i];
            int d8 = p.x & 255;
            int r = atomicAdd(&c2[d8], 1);
            int pos = rp[d8] + r;
            csr_src[pos] = (int)(p.x >> 8);
            csr_val[pos] = __uint_as_float(p.y) * dl[d8];
        }
    }
}

// ---------------- MFMA GEMM: C[n,FOUT](bf16) = dinv * (A[n,FIN] @ Wt^T) ----------------
// 32 rows/wave; mfma_f32_16x16x32_bf16; A-frag row=lane&15 k=(lane>>4)*8+j;
// B-frag col=lane&15; C/D col=lane&15 row=(lane>>4)*4+reg (m89-verified).
// AF32: layer 1 reads f32 x directly (in-register bf16 cvt) - kills the cvt pass.
// Epilogue scales each output row by dinv[row] (normalization factorization).

template <int FIN, int FOUT, bool AF32>
__global__ __launch_bounds__(256) void k_gemm_mfma(const void* __restrict__ Av,
                                                   const ushort_t* __restrict__ Wt,
                                                   const float* __restrict__ dinv,
                                                   ushort_t* __restrict__ C, int n) {
    constexpr int NT = FOUT / 16;      // col tiles
    constexpr int NK = FIN / 32;       // K steps
    const int wave = threadIdx.x >> 6;
    const int lane = threadIdx.x & 63;
    const int r0 = (blockIdx.x * 4 + wave) * 32;
    if (r0 >= n) return;

    const int l15 = lane & 15;
    const int kg  = lane >> 4;
    const int arow0 = min(r0 + l15, n - 1);        // tail clamp; bad rows never stored
    const int arow1 = min(r0 + 16 + l15, n - 1);

    f32x4 acc0[NT], acc1[NT];
#pragma unroll
    for (int c = 0; c < NT; ++c) { acc0[c] = (f32x4)(0.0f); acc1[c] = (f32x4)(0.0f); }

    const ushort_t* Bp = Wt + (size_t)l15 * FIN + kg * 8;

#pragma unroll 1   // keep rolled: full unroll hoists all B loads -> spill (R1 lesson)
    for (int ks = 0; ks < NK; ++ks) {
        bf16x8 a0, a1;
        if (AF32) {
            const float* A = (const float*)Av;
            const float* p0 = A + (size_t)arow0 * FIN + kg * 8 + ks * 32;
            const float* p1 = A + (size_t)arow1 * FIN + kg * 8 + ks * 32;
            float4 u0 = *(const float4*)p0, u1 = *(const float4*)(p0 + 4);
            float4 w0 = *(const float4*)p1, w1 = *(const float4*)(p1 + 4);
            a0[0] = (short)f2bf(u0.x); a0[1] = (short)f2bf(u0.y);
            a0[2] = (short)f2bf(u0.z); a0[3] = (short)f2bf(u0.w);
            a0[4] = (short)f2bf(u1.x); a0[5] = (short)f2bf(u1.y);
            a0[6] = (short)f2bf(u1.z); a0[7] = (short)f2bf(u1.w);
            a1[0] = (short)f2bf(w0.x); a1[1] = (short)f2bf(w0.y);
            a1[2] = (short)f2bf(w0.z); a1[3] = (short)f2bf(w0.w);
            a1[4] = (short)f2bf(w1.x); a1[5] = (short)f2bf(w1.y);
            a1[6] = (short)f2bf(w1.z); a1[7] = (short)f2bf(w1.w);
        } else {
            const ushort_t* A = (const ushort_t*)Av;
            a0 = *(const bf16x8*)(A + (size_t)arow0 * FIN + kg * 8 + ks * 32);
            a1 = *(const bf16x8*)(A + (size_t)arow1 * FIN + kg * 8 + ks * 32);
        }
#pragma unroll
        for (int c = 0; c < NT; ++c) {
            bf16x8 bfr = *(const bf16x8*)(Bp + (size_t)c * 16 * FIN + ks * 32);
            acc0[c] = __builtin_amdgcn_mfma_f32_16x16x32_bf16(a0, bfr, acc0[c], 0, 0, 0);
            acc1[c] = __builtin_amdgcn_mfma_f32_16x16x32_bf16(a1, bfr, acc1[c], 0, 0, 0);
        }
    }

#pragma unroll
    for (int g = 0; g < 2; ++g) {
        const int rbase = r0 + g * 16 + kg * 4;
#pragma unroll
        for (int j = 0; j < 4; ++j) {
            int row = rbase + j;
            if (row < n) {
                float dscale = dinv[row];
#pragma unroll
                for (int c = 0; c < NT; ++c) {
                    float val = (g == 0) ? acc0[c][j] : acc1[c][j];
                    C[(size_t)row * FOUT + c * 16 + l15] = f2bf(val * dscale);
                }
            }
        }
    }
}

// ---------------- aggregation (bf16 H', ushort4 gathers, x8-unrolled) ----------------
// out = dinv[node]*H'[node] + sum_e csr_val*H'[src] + b  (H' has dinv folded in)

template <int FOUT, bool RELU, bool OBF16>
__global__ __launch_bounds__(256) void k_agg(const ushort_t* __restrict__ H,
                                             const float* __restrict__ dinv,
                                             const int* __restrict__ rowptr,
                                             const int* __restrict__ csr_src,
                                             const float* __restrict__ csr_val,
                                             const float* __restrict__ bias,
                                             void* __restrict__ outv, int n) {
    constexpr int LPN = FOUT / 4;          // lanes per node: 32 / 16 / 8
    constexpr int NPW = 64 / LPN;          // nodes per wave: 2 / 4 / 8
    const int wave = threadIdx.x >> 6;
    const int lane = threadIdx.x & 63;
    const int sub  = lane / LPN;
    const int f4   = lane % LPN;           // feature-quad index
    const int node = (blockIdx.x * 4 + wave) * NPW + sub;
    if (node >= n) return;

    const ushort_t* __restrict__ Hf = H + 4 * f4;   // lane-fixed column base

    const float sn = dinv[node];
    ushort4 hv = *(const ushort4*)(Hf + (size_t)node * FOUT);
    float a0 = sn * bf2f(hv.x);
    float a1 = sn * bf2f(hv.y);
    float a2 = sn * bf2f(hv.z);
    float a3 = sn * bf2f(hv.w);

    const int e0 = rowptr[node], e1 = rowptr[node + 1];
    int e = e0;
    for (; e + 8 <= e1; e += 8) {
        int   s0 = csr_src[e+0], s1 = csr_src[e+1], s2 = csr_src[e+2], s3 = csr_src[e+3];
        int   s4 = csr_src[e+4], s5 = csr_src[e+5], s6 = csr_src[e+6], s7 = csr_src[e+7];
        float v0 = csr_val[e+0], v1 = csr_val[e+1], v2 = csr_val[e+2], v3 = csr_val[e+3];
        float v4 = csr_val[e+4], v5 = csr_val[e+5], v6 = csr_val[e+6], v7 = csr_val[e+7];
        ushort4 m0 = *(const ushort4*)(Hf + (size_t)s0 * FOUT);
        ushort4 m1 = *(const ushort4*)(Hf + (size_t)s1 * FOUT);
        ushort4 m2 = *(const ushort4*)(Hf + (size_t)s2 * FOUT);
        ushort4 m3 = *(const ushort4*)(Hf + (size_t)s3 * FOUT);
        ushort4 m4 = *(const ushort4*)(Hf + (size_t)s4 * FOUT);
        ushort4 m5 = *(const ushort4*)(Hf + (size_t)s5 * FOUT);
        ushort4 m6 = *(const ushort4*)(Hf + (size_t)s6 * FOUT);
        ushort4 m7 = *(const ushort4*)(Hf + (size_t)s7 * FOUT);
        a0 += v0 * bf2f(m0.x); a1 += v0 * bf2f(m0.y); a2 += v0 * bf2f(m0.z); a3 += v0 * bf2f(m0.w);
        a0 += v1 * bf2f(m1.x); a1 += v1 * bf2f(m1.y); a2 += v1 * bf2f(m1.z); a3 += v1 * bf2f(m1.w);
        a0 += v2 * bf2f(m2.x); a1 += v2 * bf2f(m2.y); a2 += v2 * bf2f(m2.z); a3 += v2 * bf2f(m2.w);
        a0 += v3 * bf2f(m3.x); a1 += v3 * bf2f(m3.y); a2 += v3 * bf2f(m3.z); a3 += v3 * bf2f(m3.w);
        a0 += v4 * bf2f(m4.x); a1 += v4 * bf2f(m4.y); a2 += v4 * bf2f(m4.z); a3 += v4 * bf2f(m4.w);
        a0 += v5 * bf2f(m5.x); a1 += v5 * bf2f(m5.y); a2 += v5 * bf2f(m5.z); a3 += v5 * bf2f(m5.w);
        a0 += v6 * bf2f(m6.x); a1 += v6 * bf2f(m6.y); a2 += v6 * bf2f(m6.z); a3 += v6 * bf2f(m6.w);
        a0 += v7 * bf2f(m7.x); a1 += v7 * bf2f(m7.y); a2 += v7 * bf2f(m7.z); a3 += v7 * bf2f(m7.w);
    }
    for (; e + 2 <= e1; e += 2) {
        int   s0 = csr_src[e+0], s1 = csr_src[e+1];
        float v0 = csr_val[e+0], v1 = csr_val[e+1];
        ushort4 m0 = *(const ushort4*)(Hf + (size_t)s0 * FOUT);
        ushort4 m1 = *(const ushort4*)(Hf + (size_t)s1 * FOUT);
        a0 += v0 * bf2f(m0.x); a1 += v0 * bf2f(m0.y); a2 += v0 * bf2f(m0.z); a3 += v0 * bf2f(m0.w);
        a0 += v1 * bf2f(m1.x); a1 += v1 * bf2f(m1.y); a2 += v1 * bf2f(m1.z); a3 += v1 * bf2f(m1.w);
    }
    if (e < e1) {
        int   s0 = csr_src[e];
        float v0 = csr_val[e];
        ushort4 m0 = *(const ushort4*)(Hf + (size_t)s0 * FOUT);
        a0 += v0 * bf2f(m0.x); a1 += v0 * bf2f(m0.y); a2 += v0 * bf2f(m0.z); a3 += v0 * bf2f(m0.w);
    }

    float4 bv = *(const float4*)(bias + 4 * f4);
    a0 += bv.x; a1 += bv.y; a2 += bv.z; a3 += bv.w;
    if (RELU) {
        a0 = fmaxf(a0, 0.f); a1 = fmaxf(a1, 0.f);
        a2 = fmaxf(a2, 0.f); a3 = fmaxf(a3, 0.f);
    }
    if (OBF16) {
        ushort4 o = make_ushort4(f2bf(a0), f2bf(a1), f2bf(a2), f2bf(a3));
        *(ushort4*)((ushort_t*)outv + (size_t)node * FOUT + 4 * f4) = o;
    } else {
        *(float4*)((float*)outv + (size_t)node * FOUT + 4 * f4) = make_float4(a0, a1, a2, a3);
    }
}

// ---------------- launch ----------------

extern "C" void kernel_launch(void* const* d_in, const int* in_sizes, int n_in,
                              void* d_out, int out_size, void* d_ws, size_t ws_size,
                              hipStream_t stream) {
    const float* x    = (const float*)d_in[0];
    const int*   eidx = (const int*)d_in[1];
    const float* ea   = (const float*)d_in[2];
    const float* W1   = (const float*)d_in[3];
    const float* b1   = (const float*)d_in[4];
    const float* W2   = (const float*)d_in[5];
    const float* b2   = (const float*)d_in[6];
    const float* W3   = (const float*)d_in[7];
    const float* b3   = (const float*)d_in[8];

    const int N = in_sizes[0] / 128;
    const int E = in_sizes[2];

    const int nbins = (N + 255) >> BIN_SHIFT;            // 196 for N=50000 (<=256)
    const int epb   = (E + SCAT_NB - 1) / SCAT_NB;       // edges per scatter block
    const int nbc   = nbins * SCAT_NB;                   // bcnt/ebofs length
    const int gBC   = (nbc + BLK - 1) / BLK;

    char*  base = (char*)d_ws;
    size_t off  = 0;
    auto carve = [&](size_t nbytes) -> void* {
        void* p = base + off;
        off = (off + nbytes + 255) & ~(size_t)255;
        return p;
    };
    int*   bcnt      = (int*)  carve((size_t)nbc * 4);
    int*   ebofs     = (int*)  carve((size_t)nbc * 4);
    int*   bsumB     = (int*)  carve((size_t)512 * 4);
    uint2* binned    = (uint2*)carve((size_t)E * 8);
    float* dinv      = (float*)carve((size_t)N * 4);
    int*   rowptr    = (int*)  carve((size_t)(N + 1) * 4);
    int*   csr_src   = (int*)  carve((size_t)E * 4);
    float* csr_val   = (float*)carve((size_t)E * 4);
    ushort_t* bufA   = (ushort_t*)carve((size_t)N * 128 * 2);   // bf16: gemm outputs H'
    ushort_t* bufB   = (ushort_t*)carve((size_t)N * 128 * 2);   // bf16: agg outputs G
    ushort_t* Wt1    = (ushort_t*)carve((size_t)128 * 128 * 2);
    ushort_t* Wt2    = (ushort_t*)carve((size_t)64 * 128 * 2);
    ushort_t* Wt3    = (ushort_t*)carve((size_t)32 * 64 * 2);
    (void)ws_size;

    const int wtot = 128 * 128 + 128 * 64 + 64 * 32;
    const int gPre = SCAT_NB + (wtot + 255) / 256;
    const int gR = (N + 127) / 128;                      // MFMA gemm blocks (128 rows/block)

    // prologue: bin_count + weight transpose/convert (one dispatch; x stays f32)
    k_pre<<<gPre, BLK, 0, stream>>>(eidx, bcnt, nbins, epb, E, W1, Wt1, W2, Wt2, W3, Wt3);
    // scan bin offsets (global offsets reconstructed inline by consumers)
    k_scan1<<<gBC, BLK, 0, stream>>>(bcnt, ebofs, bsumB, nbc);
    k_scan2x<<<1, BLK, 0, stream>>>(bsumB, gBC);
    // binned CSR build (no global atomics): scatter, then fused hist+rowptr+dinv+emit
    k_bin_scatter<<<SCAT_NB, BLK, 0, stream>>>(eidx, ea, ebofs, bsumB, binned, nbins, epb, E);
    k_bin_finish<<<nbins, BLK, 0, stream>>>(binned, ebofs, bsumB, dinv, rowptr,
                                            csr_src, csr_val, nbins, N, E);

    // layer 1: 128 -> 128, relu  (gemm reads f32 x directly)
    k_gemm_mfma<128, 128, true><<<gR, BLK, 0, stream>>>(x, Wt1, dinv, bufA, N);
    k_agg<128, true, true><<<(N + 7) / 8, BLK, 0, stream>>>(bufA, dinv, rowptr, csr_src, csr_val, b1, bufB, N);

    // layer 2: 128 -> 64, relu
    k_gemm_mfma<128, 64, false><<<gR, BLK, 0, stream>>>(bufB, Wt2, dinv, bufA, N);
    k_agg<64, true, true><<<(N + 15) / 16, BLK, 0, stream>>>(bufA, dinv, rowptr, csr_src, csr_val, b2, bufB, N);

    // layer 3: 64 -> 32, no relu
    k_gemm_mfma<64, 32, false><<<gR, BLK, 0, stream>>>(bufB, Wt3, dinv, bufA, N);
    k_agg<32, false, false><<<(N + 31) / 32, BLK, 0, stream>>>(bufA, dinv, rowptr, csr_src, csr_val, b3, d_out, N);
}